// Round 1
// 106.593 us; speedup vs baseline: 1.0343x; 1.0343x over previous
//
#include <hip/hip_runtime.h>
#include <cstdint>

#define NHEAD 8
#define HD 32
#define DM 256
#define HH 56
#define WWID 56
#define HW 3136          // 56*56
#define NB 2
#define SCALE 0.17677669529663687f   // 32^-0.5

// exp(s) == exp2(s*log2e): fold log2e into the q pre-scale so the attention
// inner loop is a bare v_exp_f32 (saves one v_mul per neighbor, 49/lane).
#if __has_builtin(__builtin_amdgcn_exp2f)
#define QSCALE 0.25503488f           // SCALE * log2(e)
#define EXPW(x) __builtin_amdgcn_exp2f(x)
#else
#define QSCALE SCALE
#define EXPW(x) __expf(x)
#endif

typedef _Float16 f16;
typedef __attribute__((ext_vector_type(2))) _Float16 f16x2;
typedef __attribute__((ext_vector_type(8))) _Float16 f16x8;   // 4 VGPRs
typedef __attribute__((ext_vector_type(4))) float floatx4;

union U16 { uint4 u; f16x2 h2[4]; f16 h[8]; };

// async global->LDS, 16B per lane. LDS dest must be wave-linear (base+lane*16).
#define GLD16(g, l) __builtin_amdgcn_global_load_lds( \
    (__attribute__((address_space(1))) void*)(g),     \
    (__attribute__((address_space(3))) void*)(l), 16, 0, 0)

// 4-lane (quad) sum via DPP quad_perm: runs on the VALU pipe instead of the
// LDS pipe (ds_swizzle), which is the attn kernel's bottleneck resource.
#if __has_builtin(__builtin_amdgcn_update_dpp)
__device__ __forceinline__ float quad_sum(float s) {
    float t1 = __int_as_float(__builtin_amdgcn_update_dpp(
        0, __float_as_int(s), 0xB1, 0xF, 0xF, true));   // quad_perm [1,0,3,2]
    s += t1;
    float t2 = __int_as_float(__builtin_amdgcn_update_dpp(
        0, __float_as_int(s), 0x4E, 0xF, 0xF, true));   // quad_perm [2,3,0,1]
    return s + t2;
}
#else
__device__ __forceinline__ float quad_sum(float s) {
    s += __shfl_xor(s, 1);
    s += __shfl_xor(s, 2);
    return s;
}
#endif

// ---------------------------------------------------------------------------
// prep: fused weight-convert + x transpose.
// bid < 1568: transpose x [b][c][p] fp32 -> xT [b][p][c] f16 (32x32 tiles).
// bid >= 1568: convert wq/wk/wv -> wcat[768][256] f16, wo -> wob f16.
// ---------------------------------------------------------------------------
__global__ __launch_bounds__(256) void prep(
    const float* __restrict__ x,
    const float* __restrict__ wq, const float* __restrict__ wk,
    const float* __restrict__ wv, const float* __restrict__ wo,
    f16* __restrict__ xT, f16* __restrict__ wcat, f16* __restrict__ wob)
{
    const int bid = blockIdx.x;
    const int t = threadIdx.x;
    if (bid < 1568) {
        __shared__ float tile[32][33];
        const int b = bid / 784, r = bid - 784 * b;
        const int ct = r / 98;
        const int p0 = (r - ct * 98) * 32, c0 = ct * 32;
        const int tx = t & 31, ty = t >> 5;           // ty in [0,8)
        const float* xb = x + (size_t)b * DM * HW;
        #pragma unroll
        for (int i = 0; i < 4; ++i)
            tile[ty + i * 8][tx] = xb[(size_t)(c0 + ty + i * 8) * HW + p0 + tx];
        __syncthreads();
        f16* xo = xT + (size_t)b * HW * DM;
        #pragma unroll
        for (int i = 0; i < 4; ++i)
            xo[(size_t)(p0 + ty + i * 8) * DM + c0 + tx] =
                (f16)tile[tx][ty + i * 8];
    } else {
        const int gid = (bid - 1568) * 256 + t;
        const int idx4 = gid << 2;                // 0 .. 262140
        const int sel = idx4 >> 16;               // 0..3
        const int off = idx4 & 65535;
        const float* src = sel == 0 ? wq : (sel == 1 ? wk : (sel == 2 ? wv : wo));
        f16* dst = sel < 3 ? (wcat + (sel << 16) + off) : (wob + off);
        float4 f = *(const float4*)&src[off];
        union { ushort4 u; f16 h[4]; } pk;
        pk.h[0] = (f16)f.x; pk.h[1] = (f16)f.y;
        pk.h[2] = (f16)f.z; pk.h[3] = (f16)f.w;
        *(ushort4*)dst = pk.u;
    }
}

// ---------------------------------------------------------------------------
// MFMA GEMM: A f16 [M][256] k-contig; B as Bm[b][n][k] k-contig.
// BM=128, BN=64, BK=32, 4 waves, wave = 64x32 via 4x2 tiles of 16x16x32_f16.
// Staging via global_load_lds width=16 (async, no VGPR round-trip).
// LDS layout is LINEAR [rows][32] (64B rows): required by global_load_lds
// (dest = wave base + lane*16) AND conflict-free for the fragment reads --
// each ds_read_b128 instruction's 64 lanes cover 16 rows x 4 quads = one
// contiguous 1KB block (every bank hit exactly 8x).
// MODE 0: M=768 fused qkv -> q/k/v f16 [b][h][p][d]; q rows pre-scaled by
//         QSCALE (= SCALE*log2e) in the epilogue.
// MODE 1: M=256 out-proj  -> fp32 d_out [b][c][p].
// ---------------------------------------------------------------------------
template<int MODE>
__global__ __launch_bounds__(256) void gemm_mfma(
    const f16* __restrict__ A,
    const f16* __restrict__ Bm,
    const float* __restrict__ b0, const float* __restrict__ b1,
    const float* __restrict__ b2,
    void* __restrict__ o0, void* __restrict__ o1, void* __restrict__ o2)
{
    const int bb = blockIdx.z;
    const int n0 = blockIdx.x * 64;
    const int m0 = blockIdx.y * 128;
    const f16* Bb = Bm + (size_t)bb * HW * DM + (size_t)n0 * DM;

    __shared__ __align__(16) f16 As[128][32];
    __shared__ __align__(16) f16 Bs[64][32];

    const int t = threadIdx.x;
    const int wave = t >> 6, lane = t & 63;
    const int quad = lane >> 4, l16 = lane & 15;
    const int mw = (wave & 1) * 64, nw = (wave >> 1) * 32;

    floatx4 acc[4][2] = {};

    const int sr = t >> 2;            // 0..63: staged row
    const int sq = (t & 3) << 3;      // f16 col offset 0/8/16/24 (16B quads)
    const f16* gA = A + (size_t)(m0 + sr) * DM + sq;
    const f16* gB = Bb + (size_t)sr * DM + sq;
    f16* lA  = &As[sr][sq];
    f16* lA2 = &As[sr + 64][sq];
    f16* lB  = &Bs[sr][sq];

    for (int k0 = 0; k0 < DM; k0 += 32) {
        GLD16(gA + k0, lA);              // A rows 0..63
        GLD16(gA + 64 * DM + k0, lA2);   // A rows 64..127
        GLD16(gB + k0, lB);              // B rows 0..63
        __syncthreads();                 // drains vmcnt -> LDS ready
        f16x8 af[4], bf[2];
        #pragma unroll
        for (int mt = 0; mt < 4; ++mt)
            af[mt] = *(const f16x8*)&As[mw + mt * 16 + l16][quad * 8];
        #pragma unroll
        for (int nt = 0; nt < 2; ++nt)
            bf[nt] = *(const f16x8*)&Bs[nw + nt * 16 + l16][quad * 8];
        #pragma unroll
        for (int mt = 0; mt < 4; ++mt)
            #pragma unroll
            for (int nt = 0; nt < 2; ++nt)
                acc[mt][nt] = __builtin_amdgcn_mfma_f32_16x16x32_f16(
                    af[mt], bf[nt], acc[mt][nt], 0, 0, 0);
        __syncthreads();
    }

    if (MODE == 0) {
        #pragma unroll
        for (int mt = 0; mt < 4; ++mt) {
            const int gm = m0 + mw + mt * 16 + quad * 4;
            const int proj = gm >> 8;
            const int c = gm & 255;
            const int h = c >> 5, d0 = c & 31;
            const float* bptr = proj == 0 ? b0 : (proj == 1 ? b1 : b2);
            f16* op = (f16*)(proj == 0 ? o0 : (proj == 1 ? o1 : o2));
            const float sc = proj == 0 ? QSCALE : 1.0f;
            const size_t base = ((size_t)(bb * NHEAD + h) * HW) * HD + d0;
            float bias[4] = {bptr[c], bptr[c + 1], bptr[c + 2], bptr[c + 3]};
            #pragma unroll
            for (int nt = 0; nt < 2; ++nt) {
                const int p = n0 + nw + nt * 16 + l16;
                union { ushort4 u; f16 h[4]; } pk;
                #pragma unroll
                for (int r = 0; r < 4; ++r)
                    pk.h[r] = (f16)((acc[mt][nt][r] + bias[r]) * sc);
                *(ushort4*)&op[base + (size_t)p * HD] = pk.u;
            }
        }
    } else {
        float* yo = (float*)o0;
        #pragma unroll
        for (int mt = 0; mt < 4; ++mt) {
            const int gc = m0 + mw + mt * 16 + quad * 4;
            #pragma unroll
            for (int r = 0; r < 4; ++r) {
                const float bias = b0[gc + r];
                #pragma unroll
                for (int nt = 0; nt < 2; ++nt) {
                    const int p = n0 + nw + nt * 16 + l16;
                    yo[(size_t)(bb * DM + gc + r) * HW + p] = acc[mt][nt][r] + bias;
                }
            }
        }
    }
}

// ---------------------------------------------------------------------------
// Stage 2: sliding-window attention, d-split across lanes.
//  - quad reduce via DPP quad_perm (VALU) instead of ds_swizzle (LDS pipe):
//    LDS-pipe cost per neighbor drops 36 -> 24 cyc/wave (the bound resource).
//  - x-validity masks hoisted out of the loops (was 49 v_cmp per lane);
//    invalid neighbors contribute exp(0)=1 to the denominator -> constant
//    7*ninvalid added once.
//  - exp2 with log2e pre-folded into q; v_rcp for the final normalize.
// Block = 448 thr = 112 positions (2 rows x 56) x 4 chunk-lanes.
// ---------------------------------------------------------------------------
#define HROWS 8                    // 2 + 6 halo
#define HPOS  (HROWS * WWID)       // 448
#define HPP   (HPOS + 6)           // 454: +3 guard positions each side

__global__ __launch_bounds__(448) void attn_win(
    const f16* __restrict__ q,
    const f16* __restrict__ k,
    const f16* __restrict__ v,
    f16* __restrict__ out)
{
    __shared__ uint4 kh[HPP * 4];   // 29,056 B
    __shared__ uint4 vh[HPP * 4];   // 29,056 B

    const int t = threadIdx.x;            // 0..447
    const int tile = blockIdx.x;          // 0..27
    const int h = blockIdx.y, b = blockIdx.z;
    const int y0 = tile * 2;
    const size_t base = (size_t)(b * NHEAD + h) * HW * HD;
    const f16* kp = k + base;
    const f16* vp = v + base;

    // ---- stage halo rows y0-3 .. y0+4 (zero y-OOB): 1792 uint4 each.
    #pragma unroll
    for (int it = 0; it < 4; ++it) {
        const int u = t + it * 448;
        const int pos = u >> 2, ch = u & 3;
        const int hr = pos / WWID;
        const int gx = pos - hr * WWID;
        const int gy = y0 - 3 + hr;
        uint4 kv = make_uint4(0, 0, 0, 0), vv = make_uint4(0, 0, 0, 0);
        if ((unsigned)gy < HH) {
            const size_t g = (size_t)(gy * WWID + gx) * HD + (ch << 3);
            kv = *(const uint4*)&kp[g];
            vv = *(const uint4*)&vp[g];
        }
        kh[u + 12] = kv;
        vh[u + 12] = vv;
    }
    if (t < 48) {   // zero guards: 3 low + 3 high positions x 4 chunks, both
        const int ps = t % 6;
        const int fi = (ps < 3 ? ps * 4 : (HPOS + ps) * 4) + ((t / 6) & 3);
        const uint4 z = make_uint4(0, 0, 0, 0);
        if (t < 24) kh[fi] = z; else vh[fi] = z;
    }
    __syncthreads();

    const int pl = t >> 2;                // local position 0..111
    const int ch = t & 3;                 // chunk 0..3
    const int lx = pl >= WWID ? pl - WWID : pl;
    const int p = y0 * WWID + pl;

    // my q chunk (8 channels, pre-scaled by QSCALE) — one coalesced uint4
    U16 qu;
    qu.u = *(const uint4*)(q + base + (size_t)p * HD + (ch << 3));

    const uint4* kb4 = kh + t;            // + (i*56+j)*4 per neighbor
    const uint4* vb4 = vh + t;

    // x-validity mask per j (loop-invariant across i). Invalid neighbors add
    // exp(0)=1 to the denominator: 7 rows x ninvalid, folded in up front.
    float wm[7];
    #pragma unroll
    for (int j = 0; j < 7; ++j)
        wm[j] = ((unsigned)(lx + j - 3) < WWID) ? 1.0f : 0.0f;
    const int nin = (lx < 3 ? 3 - lx : 0) + (lx > 52 ? lx - 52 : 0);

    float of[8] = {};
    float sum = (float)(7 * nin);
    for (int i = 0; i < 7; ++i) {
        #pragma unroll
        for (int j = 0; j < 7; ++j) {
            const int off4 = (i * WWID + j) << 2;
            U16 ku; ku.u = kb4[off4];
            float s;
            s = __builtin_amdgcn_fdot2(ku.h2[0], qu.h2[0], 0.0f, false);
            s = __builtin_amdgcn_fdot2(ku.h2[1], qu.h2[1], s, false);
            s = __builtin_amdgcn_fdot2(ku.h2[2], qu.h2[2], s, false);
            s = __builtin_amdgcn_fdot2(ku.h2[3], qu.h2[3], s, false);
            s = quad_sum(s);
            const float e = EXPW(s);
            const float wt = e * wm[j];
            sum += wt;
            U16 vu; vu.u = vb4[off4];
            of[0] = fmaf((float)vu.h[0], wt, of[0]);
            of[1] = fmaf((float)vu.h[1], wt, of[1]);
            of[2] = fmaf((float)vu.h[2], wt, of[2]);
            of[3] = fmaf((float)vu.h[3], wt, of[3]);
            of[4] = fmaf((float)vu.h[4], wt, of[4]);
            of[5] = fmaf((float)vu.h[5], wt, of[5]);
            of[6] = fmaf((float)vu.h[6], wt, of[6]);
            of[7] = fmaf((float)vu.h[7], wt, of[7]);
        }
    }

#if __has_builtin(__builtin_amdgcn_rcpf)
    const float inv = __builtin_amdgcn_rcpf(sum);
#else
    const float inv = 1.0f / sum;
#endif
    f16* op = out + ((size_t)b * HW + p) * DM + h * HD + (ch << 3);
    U16 ou;
    #pragma unroll
    for (int j = 0; j < 8; ++j)
        ou.h[j] = (f16)(of[j] * inv);
    *(uint4*)op = ou.u;
}

// ---------------------------------------------------------------------------
extern "C" void kernel_launch(void* const* d_in, const int* in_sizes, int n_in,
                              void* d_out, int out_size, void* d_ws, size_t ws_size,
                              hipStream_t stream) {
    const float* x  = (const float*)d_in[0];
    const float* wq = (const float*)d_in[1];
    const float* bq = (const float*)d_in[2];
    const float* wk = (const float*)d_in[3];
    const float* bk = (const float*)d_in[4];
    const float* wv = (const float*)d_in[5];
    const float* bv = (const float*)d_in[6];
    const float* wo = (const float*)d_in[7];
    const float* bo = (const float*)d_in[8];
    float* out = (float*)d_out;

    const size_t NPC = (size_t)NB * HW * DM;
    f16* xT    = (f16*)d_ws;               // [b][p][c]
    f16* wcat  = xT + NPC;                 // [768][256]
    f16* wob   = wcat + 768 * 256;         // [256][256]
    f16* qb    = wob + 256 * 256;          // [b][h][p][d], pre-scaled
    f16* kb    = qb + NPC;
    f16* vb    = kb + NPC;
    f16* attnT = vb + NPC;                 // [b][p][c]

    prep<<<1824, 256, 0, stream>>>(x, wq, wk, wv, wo, xT, wcat, wob);
    gemm_mfma<0><<<dim3(HW / 64, 6, NB), 256, 0, stream>>>(
        wcat, xT, bq, bk, bv, qb, kb, vb);
    attn_win<<<dim3(28, NHEAD, NB), 448, 0, stream>>>(qb, kb, vb, attnT);
    gemm_mfma<1><<<dim3(HW / 64, 2, NB), 256, 0, stream>>>(
        wob, attnT, bo, bo, bo, out, out, out);
}

// Round 2
// 105.509 us; speedup vs baseline: 1.0450x; 1.0103x over previous
//
#include <hip/hip_runtime.h>
#include <cstdint>

#define NHEAD 8
#define HD 32
#define DM 256
#define HH 56
#define WWID 56
#define HW 3136          // 56*56
#define NB 2
#define SCALE 0.17677669529663687f   // 32^-0.5

// exp(s) == exp2(s*log2e): fold log2e into the q pre-scale so the attention
// inner loop is a bare v_exp_f32.
#if __has_builtin(__builtin_amdgcn_exp2f)
#define QSCALE 0.25503488f           // SCALE * log2(e)
#define EXPW(x) __builtin_amdgcn_exp2f(x)
#else
#define QSCALE SCALE
#define EXPW(x) __expf(x)
#endif

typedef _Float16 f16;
typedef __attribute__((ext_vector_type(2))) _Float16 f16x2;
typedef __attribute__((ext_vector_type(8))) _Float16 f16x8;   // 4 VGPRs
typedef __attribute__((ext_vector_type(4))) float floatx4;

union U16 { uint4 u; f16x2 h2[4]; f16 h[8]; };

// async global->LDS, 16B per lane. LDS dest must be wave-linear (base+lane*16).
#define GLD16(g, l) __builtin_amdgcn_global_load_lds( \
    (__attribute__((address_space(1))) void*)(g),     \
    (__attribute__((address_space(3))) void*)(l), 16, 0, 0)

// 4-lane (quad) sum via DPP quad_perm: VALU pipe, not LDS pipe.
#if __has_builtin(__builtin_amdgcn_update_dpp)
__device__ __forceinline__ float quad_sum(float s) {
    float t1 = __int_as_float(__builtin_amdgcn_update_dpp(
        0, __float_as_int(s), 0xB1, 0xF, 0xF, true));   // quad_perm [1,0,3,2]
    s += t1;
    float t2 = __int_as_float(__builtin_amdgcn_update_dpp(
        0, __float_as_int(s), 0x4E, 0xF, 0xF, true));   // quad_perm [2,3,0,1]
    return s + t2;
}
#else
__device__ __forceinline__ float quad_sum(float s) {
    s += __shfl_xor(s, 1);
    s += __shfl_xor(s, 2);
    return s;
}
#endif

__device__ __forceinline__ float dot8(const U16& a, const U16& b) {
    float s = __builtin_amdgcn_fdot2(a.h2[0], b.h2[0], 0.0f, false);
    s = __builtin_amdgcn_fdot2(a.h2[1], b.h2[1], s, false);
    s = __builtin_amdgcn_fdot2(a.h2[2], b.h2[2], s, false);
    s = __builtin_amdgcn_fdot2(a.h2[3], b.h2[3], s, false);
    return s;
}

// ---------------------------------------------------------------------------
// prep: fused weight-convert + x transpose (unchanged).
// ---------------------------------------------------------------------------
__global__ __launch_bounds__(256) void prep(
    const float* __restrict__ x,
    const float* __restrict__ wq, const float* __restrict__ wk,
    const float* __restrict__ wv, const float* __restrict__ wo,
    f16* __restrict__ xT, f16* __restrict__ wcat, f16* __restrict__ wob)
{
    const int bid = blockIdx.x;
    const int t = threadIdx.x;
    if (bid < 1568) {
        __shared__ float tile[32][33];
        const int b = bid / 784, r = bid - 784 * b;
        const int ct = r / 98;
        const int p0 = (r - ct * 98) * 32, c0 = ct * 32;
        const int tx = t & 31, ty = t >> 5;           // ty in [0,8)
        const float* xb = x + (size_t)b * DM * HW;
        #pragma unroll
        for (int i = 0; i < 4; ++i)
            tile[ty + i * 8][tx] = xb[(size_t)(c0 + ty + i * 8) * HW + p0 + tx];
        __syncthreads();
        f16* xo = xT + (size_t)b * HW * DM;
        #pragma unroll
        for (int i = 0; i < 4; ++i)
            xo[(size_t)(p0 + ty + i * 8) * DM + c0 + tx] =
                (f16)tile[tx][ty + i * 8];
    } else {
        const int gid = (bid - 1568) * 256 + t;
        const int idx4 = gid << 2;                // 0 .. 262140
        const int sel = idx4 >> 16;               // 0..3
        const int off = idx4 & 65535;
        const float* src = sel == 0 ? wq : (sel == 1 ? wk : (sel == 2 ? wv : wo));
        f16* dst = sel < 3 ? (wcat + (sel << 16) + off) : (wob + off);
        float4 f = *(const float4*)&src[off];
        union { ushort4 u; f16 h[4]; } pk;
        pk.h[0] = (f16)f.x; pk.h[1] = (f16)f.y;
        pk.h[2] = (f16)f.z; pk.h[3] = (f16)f.w;
        *(ushort4*)dst = pk.u;
    }
}

// ---------------------------------------------------------------------------
// MFMA GEMM: BM=128, BN=64, BK=32, 4 waves, fragments 4x2 of 16x16x32_f16.
// NEW: double-buffered LDS + prefetch-next-tile + counted s_waitcnt vmcnt(3)
// (T3/T4 minimum 2-phase form): the 3 global_load_lds for tile k+1 stay in
// flight across the barrier while tile k's MFMAs run; only tile k's loads
// (the 3 oldest) are drained. Raw s_barrier (hip __syncthreads would emit
// vmcnt(0) and defeat the pipeline). Trailing lgkmcnt(0)+sched_barrier closes
// the cross-wave WAR before the buffer is re-staged next iteration.
// ---------------------------------------------------------------------------
template<int MODE>
__global__ __launch_bounds__(256) void gemm_mfma(
    const f16* __restrict__ A,
    const f16* __restrict__ Bm,
    const float* __restrict__ b0, const float* __restrict__ b1,
    const float* __restrict__ b2,
    void* __restrict__ o0, void* __restrict__ o1, void* __restrict__ o2)
{
    const int bb = blockIdx.z;
    const int n0 = blockIdx.x * 64;
    const int m0 = blockIdx.y * 128;
    const f16* Bb = Bm + (size_t)bb * HW * DM + (size_t)n0 * DM;

    __shared__ __align__(16) f16 As[2][128][32];
    __shared__ __align__(16) f16 Bs[2][64][32];

    const int t = threadIdx.x;
    const int wave = t >> 6, lane = t & 63;
    const int quad = lane >> 4, l16 = lane & 15;
    const int mw = (wave & 1) * 64, nw = (wave >> 1) * 32;

    floatx4 acc[4][2] = {};

    const int sr = t >> 2;            // 0..63: staged row
    const int sq = (t & 3) << 3;      // f16 col offset 0/8/16/24 (16B quads)
    const f16* gA = A + (size_t)(m0 + sr) * DM + sq;
    const f16* gB = Bb + (size_t)sr * DM + sq;
    f16* lA[2]  = { &As[0][sr][sq],      &As[1][sr][sq]      };
    f16* lA2[2] = { &As[0][sr + 64][sq], &As[1][sr + 64][sq] };
    f16* lB[2]  = { &Bs[0][sr][sq],      &Bs[1][sr][sq]      };

    // prologue: stage tile 0 into buffer 0
    GLD16(gA, lA[0]);
    GLD16(gA + 64 * DM, lA2[0]);
    GLD16(gB, lB[0]);

    #pragma unroll
    for (int kk = 0; kk < 8; ++kk) {
        const int cur = kk & 1, nxt = cur ^ 1;
        if (kk < 7) {               // prefetch tile kk+1 into the other buffer
            const int ko = (kk + 1) * 32;
            GLD16(gA + ko, lA[nxt]);
            GLD16(gA + 64 * DM + ko, lA2[nxt]);
            GLD16(gB + ko, lB[nxt]);
            asm volatile("s_waitcnt vmcnt(3)" ::: "memory");  // tile kk landed
        } else {
            asm volatile("s_waitcnt vmcnt(0)" ::: "memory");
        }
        __builtin_amdgcn_s_barrier();
        __builtin_amdgcn_sched_barrier(0);
        f16x8 af[4], bf[2];
        #pragma unroll
        for (int mt = 0; mt < 4; ++mt)
            af[mt] = *(const f16x8*)&As[cur][mw + mt * 16 + l16][quad * 8];
        #pragma unroll
        for (int nt = 0; nt < 2; ++nt)
            bf[nt] = *(const f16x8*)&Bs[cur][nw + nt * 16 + l16][quad * 8];
        #pragma unroll
        for (int mt = 0; mt < 4; ++mt)
            #pragma unroll
            for (int nt = 0; nt < 2; ++nt)
                acc[mt][nt] = __builtin_amdgcn_mfma_f32_16x16x32_f16(
                    af[mt], bf[nt], acc[mt][nt], 0, 0, 0);
        asm volatile("s_waitcnt lgkmcnt(0)" ::: "memory");   // frag reads done
        __builtin_amdgcn_sched_barrier(0);
        __builtin_amdgcn_s_barrier();   // buffer 'cur' may now be re-staged
    }

    if (MODE == 0) {
        #pragma unroll
        for (int mt = 0; mt < 4; ++mt) {
            const int gm = m0 + mw + mt * 16 + quad * 4;
            const int proj = gm >> 8;
            const int c = gm & 255;
            const int h = c >> 5, d0 = c & 31;
            const float* bptr = proj == 0 ? b0 : (proj == 1 ? b1 : b2);
            f16* op = (f16*)(proj == 0 ? o0 : (proj == 1 ? o1 : o2));
            const float sc = proj == 0 ? QSCALE : 1.0f;
            const size_t base = ((size_t)(bb * NHEAD + h) * HW) * HD + d0;
            float bias[4] = {bptr[c], bptr[c + 1], bptr[c + 2], bptr[c + 3]};
            #pragma unroll
            for (int nt = 0; nt < 2; ++nt) {
                const int p = n0 + nw + nt * 16 + l16;
                union { ushort4 u; f16 h[4]; } pk;
                #pragma unroll
                for (int r = 0; r < 4; ++r)
                    pk.h[r] = (f16)((acc[mt][nt][r] + bias[r]) * sc);
                *(ushort4*)&op[base + (size_t)p * HD] = pk.u;
            }
        }
    } else {
        float* yo = (float*)o0;
        #pragma unroll
        for (int mt = 0; mt < 4; ++mt) {
            const int gc = m0 + mw + mt * 16 + quad * 4;
            #pragma unroll
            for (int r = 0; r < 4; ++r) {
                const float bias = b0[gc + r];
                #pragma unroll
                for (int nt = 0; nt < 2; ++nt) {
                    const int p = n0 + nw + nt * 16 + l16;
                    yo[(size_t)(bb * DM + gc + r) * HW + p] = acc[mt][nt][r] + bias;
                }
            }
        }
    }
}

// ---------------------------------------------------------------------------
// Stage 2: sliding-window attention, d-split across lanes, x-PAIRED:
// each 4-lane group computes TWO adjacent positions (x0, x0+1). Their window
// columns overlap 6/7; the 8-column union is read from LDS once and serves
// both dots -> LDS group-reads/position drop 98 -> 56 (-43%), and LDS b128
// throughput (85 B/cyc/CU) is this kernel's bound resource. VALU per position
// unchanged. Column c of the union maps to jA=c (valid c<7) / jB=c-1 (valid
// c>0); both share the validity mask inr[c] = (x0+c-3) in [0,56).
// Block = 224 thr = 2 rows x 28 pairs x 4 chunk-lanes. LDS layout, halo and
// flat-index trick unchanged; max LDS index = 443 + (6*56+7)*4 = 1815 (last
// element, in bounds).
// ---------------------------------------------------------------------------
#define HROWS 8                    // 2 + 6 halo
#define HPOS  (HROWS * WWID)       // 448
#define HPP   (HPOS + 6)           // 454: +3 guard positions each side

__global__ __launch_bounds__(224) void attn_win(
    const f16* __restrict__ q,
    const f16* __restrict__ k,
    const f16* __restrict__ v,
    f16* __restrict__ out)
{
    __shared__ uint4 kh[HPP * 4];   // 29,056 B
    __shared__ uint4 vh[HPP * 4];   // 29,056 B

    const int t = threadIdx.x;            // 0..223
    const int tile = blockIdx.x;          // 0..27
    const int h = blockIdx.y, b = blockIdx.z;
    const int y0 = tile * 2;
    const size_t base = (size_t)(b * NHEAD + h) * HW * HD;
    const f16* kp = k + base;
    const f16* vp = v + base;

    // ---- stage halo rows y0-3 .. y0+4 (zero y-OOB): 1792 uint4 each.
    #pragma unroll
    for (int it = 0; it < 8; ++it) {
        const int u = t + it * 224;
        const int pos = u >> 2, ch = u & 3;
        const int hr = pos / WWID;
        const int gx = pos - hr * WWID;
        const int gy = y0 - 3 + hr;
        uint4 kv = make_uint4(0, 0, 0, 0), vv = make_uint4(0, 0, 0, 0);
        if ((unsigned)gy < HH) {
            const size_t g = (size_t)(gy * WWID + gx) * HD + (ch << 3);
            kv = *(const uint4*)&kp[g];
            vv = *(const uint4*)&vp[g];
        }
        kh[u + 12] = kv;
        vh[u + 12] = vv;
    }
    if (t < 48) {   // zero guards: 3 low + 3 high positions x 4 chunks, both
        const int ps = t % 6;
        const int fi = (ps < 3 ? ps * 4 : (HPOS + ps) * 4) + ((t / 6) & 3);
        const uint4 z = make_uint4(0, 0, 0, 0);
        if (t < 24) kh[fi] = z; else vh[fi] = z;
    }
    __syncthreads();

    const int g  = t >> 2;                // group 0..55
    const int ch = t & 3;                 // chunk 0..3
    const int ry = g >= 28 ? 1 : 0;       // local row
    const int px = g - ry * 28;           // pair index 0..27
    const int x0 = px * 2;                // position A x; B = x0+1
    const int plA = ry * WWID + x0;       // local position of A
    const int pA = y0 * WWID + plA;       // global position of A
    const int tA = plA * 4 + ch;          // LDS flat base for A

    // q chunks for both positions (pre-scaled by QSCALE)
    U16 qa, qb;
    qa.u = *(const uint4*)(q + base + (size_t)pA * HD + (ch << 3));
    qb.u = *(const uint4*)(q + base + (size_t)(pA + 1) * HD + (ch << 3));

    const uint4* kb4 = kh + tA;           // + (i*56+c)*4 per union column
    const uint4* vb4 = vh + tA;

    // shared x-validity mask for union column c; invalid neighbors contribute
    // exp(0)=1 to the denominator -> folded in as 7 * (#invalid).
    float inr[8];
    float cA = 0.f, cB = 0.f;
    #pragma unroll
    for (int c = 0; c < 8; ++c) {
        inr[c] = ((unsigned)(x0 + c - 3) < WWID) ? 1.0f : 0.0f;
        if (c < 7) cA += inr[c];
        if (c > 0) cB += inr[c];
    }
    float ofA[8] = {}, ofB[8] = {};
    float sumA = 7.0f * (7.0f - cA);
    float sumB = 7.0f * (7.0f - cB);

    for (int i = 0; i < 7; ++i) {
        #pragma unroll
        for (int c = 0; c < 8; ++c) {
            const int off4 = (i * WWID + c) << 2;
            U16 ku; ku.u = kb4[off4];
            U16 vu; vu.u = vb4[off4];
            if (c < 7) {                          // position A, jA = c
                float s = quad_sum(dot8(ku, qa));
                const float w = EXPW(s) * inr[c];
                sumA += w;
                #pragma unroll
                for (int n = 0; n < 8; ++n)
                    ofA[n] = fmaf((float)vu.h[n], w, ofA[n]);
            }
            if (c > 0) {                          // position B, jB = c-1
                float s = quad_sum(dot8(ku, qb));
                const float w = EXPW(s) * inr[c];
                sumB += w;
                #pragma unroll
                for (int n = 0; n < 8; ++n)
                    ofB[n] = fmaf((float)vu.h[n], w, ofB[n]);
            }
        }
    }

#if __has_builtin(__builtin_amdgcn_rcpf)
    const float invA = __builtin_amdgcn_rcpf(sumA);
    const float invB = __builtin_amdgcn_rcpf(sumB);
#else
    const float invA = 1.0f / sumA;
    const float invB = 1.0f / sumB;
#endif
    f16* opA = out + ((size_t)b * HW + pA) * DM + h * HD + (ch << 3);
    f16* opB = opA + DM;
    U16 oa, ob;
    #pragma unroll
    for (int n = 0; n < 8; ++n) {
        oa.h[n] = (f16)(ofA[n] * invA);
        ob.h[n] = (f16)(ofB[n] * invB);
    }
    *(uint4*)opA = oa.u;
    *(uint4*)opB = ob.u;
}

// ---------------------------------------------------------------------------
extern "C" void kernel_launch(void* const* d_in, const int* in_sizes, int n_in,
                              void* d_out, int out_size, void* d_ws, size_t ws_size,
                              hipStream_t stream) {
    const float* x  = (const float*)d_in[0];
    const float* wq = (const float*)d_in[1];
    const float* bq = (const float*)d_in[2];
    const float* wk = (const float*)d_in[3];
    const float* bk = (const float*)d_in[4];
    const float* wv = (const float*)d_in[5];
    const float* bv = (const float*)d_in[6];
    const float* wo = (const float*)d_in[7];
    const float* bo = (const float*)d_in[8];
    float* out = (float*)d_out;

    const size_t NPC = (size_t)NB * HW * DM;
    f16* xT    = (f16*)d_ws;               // [b][p][c]
    f16* wcat  = xT + NPC;                 // [768][256]
    f16* wob   = wcat + 768 * 256;         // [256][256]
    f16* qb    = wob + 256 * 256;          // [b][h][p][d], pre-scaled
    f16* kb    = qb + NPC;
    f16* vb    = kb + NPC;
    f16* attnT = vb + NPC;                 // [b][p][c]

    prep<<<1824, 256, 0, stream>>>(x, wq, wk, wv, wo, xT, wcat, wob);
    gemm_mfma<0><<<dim3(HW / 64, 6, NB), 256, 0, stream>>>(
        wcat, xT, bq, bk, bv, qb, kb, vb);
    attn_win<<<dim3(28, NHEAD, NB), 224, 0, stream>>>(qb, kb, vb, attnT);
    gemm_mfma<1><<<dim3(HW / 64, 2, NB), 256, 0, stream>>>(
        wob, attnT, bo, bo, bo, out, out, out);
}

// Round 3
// 102.813 us; speedup vs baseline: 1.0724x; 1.0262x over previous
//
#include <hip/hip_runtime.h>
#include <cstdint>

#define NHEAD 8
#define HD 32
#define DM 256
#define HH 56
#define WWID 56
#define HW 3136          // 56*56
#define NB 2
#define SCALE 0.17677669529663687f   // 32^-0.5

// exp(s) == exp2(s*log2e): fold log2e into the q pre-scale so the attention
// inner loop is a bare v_exp_f32.
#if __has_builtin(__builtin_amdgcn_exp2f)
#define QSCALE 0.25503488f           // SCALE * log2(e)
#define EXPW(x) __builtin_amdgcn_exp2f(x)
#else
#define QSCALE SCALE
#define EXPW(x) __expf(x)
#endif

typedef _Float16 f16;
typedef __attribute__((ext_vector_type(2))) _Float16 f16x2;
typedef __attribute__((ext_vector_type(8))) _Float16 f16x8;   // 4 VGPRs
typedef __attribute__((ext_vector_type(4))) float floatx4;

union U16 { uint4 u; f16x2 h2[4]; f16 h[8]; };

// async global->LDS, 16B per lane. LDS dest must be wave-linear (base+lane*16).
#define GLD16(g, l) __builtin_amdgcn_global_load_lds( \
    (__attribute__((address_space(1))) void*)(g),     \
    (__attribute__((address_space(3))) void*)(l), 16, 0, 0)

// 4-lane (quad) sum via DPP quad_perm: VALU pipe, not LDS pipe.
#if __has_builtin(__builtin_amdgcn_update_dpp)
__device__ __forceinline__ float quad_sum(float s) {
    float t1 = __int_as_float(__builtin_amdgcn_update_dpp(
        0, __float_as_int(s), 0xB1, 0xF, 0xF, true));   // quad_perm [1,0,3,2]
    s += t1;
    float t2 = __int_as_float(__builtin_amdgcn_update_dpp(
        0, __float_as_int(s), 0x4E, 0xF, 0xF, true));   // quad_perm [2,3,0,1]
    return s + t2;
}
#else
__device__ __forceinline__ float quad_sum(float s) {
    s += __shfl_xor(s, 1);
    s += __shfl_xor(s, 2);
    return s;
}
#endif

__device__ __forceinline__ float dot8(const U16& a, const U16& b) {
    float s = __builtin_amdgcn_fdot2(a.h2[0], b.h2[0], 0.0f, false);
    s = __builtin_amdgcn_fdot2(a.h2[1], b.h2[1], s, false);
    s = __builtin_amdgcn_fdot2(a.h2[2], b.h2[2], s, false);
    s = __builtin_amdgcn_fdot2(a.h2[3], b.h2[3], s, false);
    return s;
}

// ---------------------------------------------------------------------------
// prep: fused weight-convert + x transpose + zero-scratch init.
// ---------------------------------------------------------------------------
__global__ __launch_bounds__(256) void prep(
    const float* __restrict__ x,
    const float* __restrict__ wq, const float* __restrict__ wk,
    const float* __restrict__ wv, const float* __restrict__ wo,
    f16* __restrict__ xT, f16* __restrict__ wcat, f16* __restrict__ wob,
    f16* __restrict__ zbuf)
{
    const int bid = blockIdx.x;
    const int t = threadIdx.x;
    if (bid < 1568) {
        __shared__ float tile[32][33];
        const int b = bid / 784, r = bid - 784 * b;
        const int ct = r / 98;
        const int p0 = (r - ct * 98) * 32, c0 = ct * 32;
        const int tx = t & 31, ty = t >> 5;           // ty in [0,8)
        const float* xb = x + (size_t)b * DM * HW;
        #pragma unroll
        for (int i = 0; i < 4; ++i)
            tile[ty + i * 8][tx] = xb[(size_t)(c0 + ty + i * 8) * HW + p0 + tx];
        __syncthreads();
        f16* xo = xT + (size_t)b * HW * DM;
        #pragma unroll
        for (int i = 0; i < 4; ++i)
            xo[(size_t)(p0 + ty + i * 8) * DM + c0 + tx] =
                (f16)tile[tx][ty + i * 8];
    } else {
        if (bid == 1823 && t < 4)        // 64B zero scratch for attn OOB rows
            ((uint4*)zbuf)[t] = make_uint4(0, 0, 0, 0);
        const int gid = (bid - 1568) * 256 + t;
        const int idx4 = gid << 2;                // 0 .. 262140
        const int sel = idx4 >> 16;               // 0..3
        const int off = idx4 & 65535;
        const float* src = sel == 0 ? wq : (sel == 1 ? wk : (sel == 2 ? wv : wo));
        f16* dst = sel < 3 ? (wcat + (sel << 16) + off) : (wob + off);
        float4 f = *(const float4*)&src[off];
        union { ushort4 u; f16 h[4]; } pk;
        pk.h[0] = (f16)f.x; pk.h[1] = (f16)f.y;
        pk.h[2] = (f16)f.z; pk.h[3] = (f16)f.w;
        *(ushort4*)dst = pk.u;
    }
}

// ---------------------------------------------------------------------------
// MFMA GEMM: BM=128, BN=64, 4 waves, fragments 4x2 of 16x16x32_f16.
// BK=64 stored as TWO [rows][32] planes: keeps the 64B-row (bank-optimal)
// layout and the GLD16-linear dest, while halving the barrier/waitcnt count
// (4 sync pairs instead of 8 — barrier drain was a large fixed cost at only
// 8 K-steps). Double-buffered; counted s_waitcnt vmcnt(6) (6 loads per tile
// stay in flight across the barrier, never drained to 0 in the loop).
// ---------------------------------------------------------------------------
template<int MODE>
__global__ __launch_bounds__(256) void gemm_mfma(
    const f16* __restrict__ A,
    const f16* __restrict__ Bm,
    const float* __restrict__ b0, const float* __restrict__ b1,
    const float* __restrict__ b2,
    void* __restrict__ o0, void* __restrict__ o1, void* __restrict__ o2)
{
    const int bb = blockIdx.z;
    const int n0 = blockIdx.x * 64;
    const int m0 = blockIdx.y * 128;
    const f16* Bb = Bm + (size_t)bb * HW * DM + (size_t)n0 * DM;

    __shared__ __align__(16) f16 As[2][2][128][32];   // 32 KB
    __shared__ __align__(16) f16 Bs[2][2][64][32];    // 16 KB

    const int t = threadIdx.x;
    const int wave = t >> 6, lane = t & 63;
    const int quad = lane >> 4, l16 = lane & 15;
    const int mw = (wave & 1) * 64, nw = (wave >> 1) * 32;

    floatx4 acc[4][2] = {};

    const int sr = t >> 2;            // 0..63: staged row
    const int sq = (t & 3) << 3;      // f16 col offset 0/8/16/24 (16B quads)
    const f16* gA = A + (size_t)(m0 + sr) * DM + sq;
    const f16* gB = Bb + (size_t)sr * DM + sq;

#define STAGE(buf, k0)                                           \
    GLD16(gA + (k0),                 &As[buf][0][sr][sq]);       \
    GLD16(gA + 64 * DM + (k0),       &As[buf][0][sr + 64][sq]);  \
    GLD16(gA + (k0) + 32,            &As[buf][1][sr][sq]);       \
    GLD16(gA + 64 * DM + (k0) + 32,  &As[buf][1][sr + 64][sq]);  \
    GLD16(gB + (k0),                 &Bs[buf][0][sr][sq]);       \
    GLD16(gB + (k0) + 32,            &Bs[buf][1][sr][sq]);

    STAGE(0, 0)                       // prologue: tile 0 -> buffer 0

    #pragma unroll
    for (int kk = 0; kk < 4; ++kk) {
        const int cur = kk & 1;
        if (kk < 3) {                 // prefetch tile kk+1 into other buffer
            const int ko = (kk + 1) * 64;
            if (cur == 0) { STAGE(1, ko) } else { STAGE(0, ko) }
            asm volatile("s_waitcnt vmcnt(6)" ::: "memory");  // tile kk landed
        } else {
            asm volatile("s_waitcnt vmcnt(0)" ::: "memory");
        }
        __builtin_amdgcn_s_barrier();
        __builtin_amdgcn_sched_barrier(0);
        #pragma unroll
        for (int s = 0; s < 2; ++s) {
            f16x8 af[4], bf[2];
            #pragma unroll
            for (int mt = 0; mt < 4; ++mt)
                af[mt] = *(const f16x8*)&As[cur][s][mw + mt * 16 + l16][quad * 8];
            #pragma unroll
            for (int nt = 0; nt < 2; ++nt)
                bf[nt] = *(const f16x8*)&Bs[cur][s][nw + nt * 16 + l16][quad * 8];
            #pragma unroll
            for (int mt = 0; mt < 4; ++mt)
                #pragma unroll
                for (int nt = 0; nt < 2; ++nt)
                    acc[mt][nt] = __builtin_amdgcn_mfma_f32_16x16x32_f16(
                        af[mt], bf[nt], acc[mt][nt], 0, 0, 0);
        }
        asm volatile("s_waitcnt lgkmcnt(0)" ::: "memory");   // frag reads done
        __builtin_amdgcn_sched_barrier(0);
        __builtin_amdgcn_s_barrier();   // buffer 'cur' may now be re-staged
    }
#undef STAGE

    if (MODE == 0) {
        #pragma unroll
        for (int mt = 0; mt < 4; ++mt) {
            const int gm = m0 + mw + mt * 16 + quad * 4;
            const int proj = gm >> 8;
            const int c = gm & 255;
            const int h = c >> 5, d0 = c & 31;
            const float* bptr = proj == 0 ? b0 : (proj == 1 ? b1 : b2);
            f16* op = (f16*)(proj == 0 ? o0 : (proj == 1 ? o1 : o2));
            const float sc = proj == 0 ? QSCALE : 1.0f;
            const size_t base = ((size_t)(bb * NHEAD + h) * HW) * HD + d0;
            float bias[4] = {bptr[c], bptr[c + 1], bptr[c + 2], bptr[c + 3]};
            #pragma unroll
            for (int nt = 0; nt < 2; ++nt) {
                const int p = n0 + nw + nt * 16 + l16;
                union { ushort4 u; f16 h[4]; } pk;
                #pragma unroll
                for (int r = 0; r < 4; ++r)
                    pk.h[r] = (f16)((acc[mt][nt][r] + bias[r]) * sc);
                *(ushort4*)&op[base + (size_t)p * HD] = pk.u;
            }
        }
    } else {
        float* yo = (float*)o0;
        #pragma unroll
        for (int mt = 0; mt < 4; ++mt) {
            const int gc = m0 + mw + mt * 16 + quad * 4;
            #pragma unroll
            for (int r = 0; r < 4; ++r) {
                const float bias = b0[gc + r];
                #pragma unroll
                for (int nt = 0; nt < 2; ++nt) {
                    const int p = n0 + nw + nt * 16 + l16;
                    yo[(size_t)(bb * DM + gc + r) * HW + p] = acc[mt][nt][r] + bias;
                }
            }
        }
    }
}

// ---------------------------------------------------------------------------
// Stage 2: sliding-window attention, d-split across lanes, x-paired.
// NEW vs R2: 4-row tiles, 448 threads = 7 FULL waves (was 224 thr = 3.5
// waves: half-wave wasted 1/8 of SIMD slots), and halo staging per compute
// row drops from 4 to 2.5 rows (-37%). Staging now uses global_load_lds
// (dest (u+12)*16 is exactly wave-linear); y-OOB rows redirect the SOURCE
// to a 64B zero scratch so the load is unconditional.
// LDS 72.4 KB (1 block/CU). Flat-index bound: max tA 891 + max off 1372 =
// 2263 = last element of [566*4]. Grid = 14 x 8 x 2.
// ---------------------------------------------------------------------------
#define HROWS 10                   // 4 + 6 halo
#define HPOS  (HROWS * WWID)       // 560
#define HPP   (HPOS + 6)           // 566: +3 guard positions each side

__global__ __launch_bounds__(448) void attn_win(
    const f16* __restrict__ q,
    const f16* __restrict__ k,
    const f16* __restrict__ v,
    f16* __restrict__ out,
    const f16* __restrict__ zbuf)
{
    __shared__ uint4 kh[HPP * 4];   // 36,224 B
    __shared__ uint4 vh[HPP * 4];   // 36,224 B

    const int t = threadIdx.x;            // 0..447
    const int tile = blockIdx.x;          // 0..13
    const int h = blockIdx.y, b = blockIdx.z;
    const int y0 = tile * 4;
    const size_t base = (size_t)(b * NHEAD + h) * HW * HD;
    const f16* kp = k + base;
    const f16* vp = v + base;

    // ---- stage halo rows y0-3 .. y0+6 (zero-source for y-OOB): 2240 uint4.
    #pragma unroll
    for (int it = 0; it < 5; ++it) {
        const int u = t + it * 448;
        const int pos = u >> 2, ch = u & 3;
        const int hr = pos / WWID;
        const int gx = pos - hr * WWID;
        const int gy = y0 - 3 + hr;
        const bool val = (unsigned)gy < HH;
        const size_t g = (size_t)(gy * WWID + gx) * HD + (ch << 3);
        const f16* ks = val ? kp + g : zbuf;
        const f16* vs = val ? vp + g : zbuf;
        GLD16(ks, (f16*)&kh[u + 12]);
        GLD16(vs, (f16*)&vh[u + 12]);
    }
    if (t < 48) {   // zero guards: 3 low + 3 high positions x 4 chunks, both
        const int ps = t % 6;
        const int fi = (ps < 3 ? ps * 4 : (HPOS + ps) * 4) + ((t / 6) & 3);
        const uint4 z = make_uint4(0, 0, 0, 0);
        if (t < 24) kh[fi] = z; else vh[fi] = z;
    }
    __syncthreads();                      // drains vmcnt -> halo ready

    const int g  = t >> 2;                // group 0..111
    const int ch = t & 3;                 // chunk 0..3
    const int ry = g / 28;                // local row 0..3
    const int px = g - ry * 28;           // pair index 0..27
    const int x0 = px * 2;                // position A x; B = x0+1
    const int plA = ry * WWID + x0;       // local position of A
    const int pA = y0 * WWID + plA;       // global position of A
    const int tA = plA * 4 + ch;          // LDS flat base for A

    // q chunks for both positions (pre-scaled by QSCALE)
    U16 qa, qb;
    qa.u = *(const uint4*)(q + base + (size_t)pA * HD + (ch << 3));
    qb.u = *(const uint4*)(q + base + (size_t)(pA + 1) * HD + (ch << 3));

    const uint4* kb4 = kh + tA;           // + (i*56+c)*4 per union column
    const uint4* vb4 = vh + tA;

    // shared x-validity mask for union column c; invalid neighbors contribute
    // exp(0)=1 to the denominator -> folded in as 7 * (#invalid).
    float inr[8];
    float cA = 0.f, cB = 0.f;
    #pragma unroll
    for (int c = 0; c < 8; ++c) {
        inr[c] = ((unsigned)(x0 + c - 3) < WWID) ? 1.0f : 0.0f;
        if (c < 7) cA += inr[c];
        if (c > 0) cB += inr[c];
    }
    float ofA[8] = {}, ofB[8] = {};
    float sumA = 7.0f * (7.0f - cA);
    float sumB = 7.0f * (7.0f - cB);

    for (int i = 0; i < 7; ++i) {
        #pragma unroll
        for (int c = 0; c < 8; ++c) {
            const int off4 = (i * WWID + c) << 2;
            U16 ku; ku.u = kb4[off4];
            U16 vu; vu.u = vb4[off4];
            if (c < 7) {                          // position A, jA = c
                float s = quad_sum(dot8(ku, qa));
                const float w = EXPW(s) * inr[c];
                sumA += w;
                #pragma unroll
                for (int n = 0; n < 8; ++n)
                    ofA[n] = fmaf((float)vu.h[n], w, ofA[n]);
            }
            if (c > 0) {                          // position B, jB = c-1
                float s = quad_sum(dot8(ku, qb));
                const float w = EXPW(s) * inr[c];
                sumB += w;
                #pragma unroll
                for (int n = 0; n < 8; ++n)
                    ofB[n] = fmaf((float)vu.h[n], w, ofB[n]);
            }
        }
    }

#if __has_builtin(__builtin_amdgcn_rcpf)
    const float invA = __builtin_amdgcn_rcpf(sumA);
    const float invB = __builtin_amdgcn_rcpf(sumB);
#else
    const float invA = 1.0f / sumA;
    const float invB = 1.0f / sumB;
#endif
    f16* opA = out + ((size_t)b * HW + pA) * DM + h * HD + (ch << 3);
    f16* opB = opA + DM;
    U16 oa, ob;
    #pragma unroll
    for (int n = 0; n < 8; ++n) {
        oa.h[n] = (f16)(ofA[n] * invA);
        ob.h[n] = (f16)(ofB[n] * invB);
    }
    *(uint4*)opA = oa.u;
    *(uint4*)opB = ob.u;
}

// ---------------------------------------------------------------------------
extern "C" void kernel_launch(void* const* d_in, const int* in_sizes, int n_in,
                              void* d_out, int out_size, void* d_ws, size_t ws_size,
                              hipStream_t stream) {
    const float* x  = (const float*)d_in[0];
    const float* wq = (const float*)d_in[1];
    const float* bq = (const float*)d_in[2];
    const float* wk = (const float*)d_in[3];
    const float* bk = (const float*)d_in[4];
    const float* wv = (const float*)d_in[5];
    const float* bv = (const float*)d_in[6];
    const float* wo = (const float*)d_in[7];
    const float* bo = (const float*)d_in[8];
    float* out = (float*)d_out;

    const size_t NPC = (size_t)NB * HW * DM;
    f16* xT    = (f16*)d_ws;               // [b][p][c]
    f16* wcat  = xT + NPC;                 // [768][256]
    f16* wob   = wcat + 768 * 256;         // [256][256]
    f16* qb    = wob + 256 * 256;          // [b][h][p][d], pre-scaled
    f16* kb    = qb + NPC;
    f16* vb    = kb + NPC;
    f16* attnT = vb + NPC;                 // [b][p][c]
    f16* zbuf  = attnT + NPC;              // 64B zero scratch

    prep<<<1824, 256, 0, stream>>>(x, wq, wk, wv, wo, xT, wcat, wob, zbuf);
    gemm_mfma<0><<<dim3(HW / 64, 6, NB), 256, 0, stream>>>(
        wcat, xT, bq, bk, bv, qb, kb, vb);
    attn_win<<<dim3(14, NHEAD, NB), 448, 0, stream>>>(qb, kb, vb, attnT, zbuf);
    gemm_mfma<1><<<dim3(HW / 64, 2, NB), 256, 0, stream>>>(
        wob, attnT, bo, bo, bo, out, out, out);
}